// Round 2
// baseline (733.926 us; speedup 1.0000x reference)
//
#include <hip/hip_runtime.h>
#include <hip/hip_bf16.h>

#define HIDDEN 896
#define HEADS 7
#define HDIM 128
#define BB 4
#define TT 2048
#define MTOT (BB*TT)   // 8192

typedef short bf16x8 __attribute__((ext_vector_type(8)));
typedef float f32x4 __attribute__((ext_vector_type(4)));

__device__ __forceinline__ short f2bf(float f) {
    union { float f; unsigned u; } v; v.f = f;
    unsigned r = (v.u + 0x7FFF + ((v.u >> 16) & 1)) >> 16;
    return (short)r;
}

// ---------------- kernel 1: cast x (fp32) -> bf16 ----------------
__global__ __launch_bounds__(256) void cast_x_kernel(const float* __restrict__ x,
                                                     short* __restrict__ xb) {
    int base = (blockIdx.x * 256 + threadIdx.x) * 4;
    if (base < MTOT * HIDDEN) {
        float4 v = *(const float4*)(x + base);
        short4 o;
        o.x = f2bf(v.x); o.y = f2bf(v.y); o.z = f2bf(v.z); o.w = f2bf(v.w);
        *(short4*)(xb + base) = o;
    }
}

// cast Wo fp32[896][896] -> bf16 (already B^T form [n][k])
__global__ __launch_bounds__(256) void cast_wo_kernel(const float* __restrict__ src,
                                                      short* __restrict__ dst) {
    int base = (blockIdx.x * 256 + threadIdx.x) * 4;
    if (base < HIDDEN * HIDDEN) {
        float4 v = *(const float4*)(src + base);
        short4 o;
        o.x = f2bf(v.x); o.y = f2bf(v.y); o.z = f2bf(v.z); o.w = f2bf(v.w);
        *(short4*)(dst + base) = o;
    }
}

// transpose-cast Wq/Wk/Wv fp32 [head][896 k][128 n] -> bf16 Wt[type*7+head][128 n][896 k]
__global__ __launch_bounds__(256) void transpose_cast_w(
    const float* __restrict__ Wq, const float* __restrict__ Wk,
    const float* __restrict__ Wv, short* __restrict__ Wt)
{
    __shared__ float tile[32][33];
    const int z = blockIdx.z;
    const int type = z / 7, head = z % 7;
    const float* src = (type == 0 ? Wq : (type == 1 ? Wk : Wv)) + head * (HIDDEN * HDIM);
    short* dst = Wt + (size_t)z * (HDIM * HIDDEN);
    const int r0 = blockIdx.x * 32, c0 = blockIdx.y * 32;
    const int tx = threadIdx.x & 31, ty = threadIdx.x >> 5;  // 32 x 8
    for (int i = 0; i < 4; i++)
        tile[ty * 4 + i][tx] = src[(r0 + ty * 4 + i) * HDIM + c0 + tx];
    __syncthreads();
    for (int i = 0; i < 4; i++)
        dst[(c0 + ty * 4 + i) * HIDDEN + r0 + tx] = f2bf(tile[tx][ty * 4 + i]);
}

// ---------------- kernel 2: QKV projection GEMM (128x128 tile) ----------------
// C[m][n] = sum_k xb[m][k] * Wt[z][n][k]; grid (64, 21), block 256 (2x2 waves of 64x64)
__global__ __launch_bounds__(256) void qkv_gemm(
    const short* __restrict__ xb, const short* __restrict__ Wt,
    short* __restrict__ Q, short* __restrict__ Kk, short* __restrict__ Vt)
{
    __shared__ short Ash[128 * 40];
    __shared__ short Bsh[128 * 40];
    const int m0 = blockIdx.x * 128;
    const int z = blockIdx.y;
    const int head = z % 7, type = z / 7;
    const short* Wz = Wt + (size_t)z * (HDIM * HIDDEN);

    const int tid = threadIdx.x;
    const int wave = tid >> 6, lane = tid & 63;
    const int quad = lane >> 4, l16 = lane & 15;
    const int wm = (wave >> 1) * 64, wn = (wave & 1) * 64;

    f32x4 acc[4][4] = {};

    const int sr = tid >> 2, sc = (tid & 3) * 8;   // staging row/col-chunk

    for (int k0 = 0; k0 < HIDDEN; k0 += 32) {
        bf16x8 a0 = *(const bf16x8*)(xb + (size_t)(m0 + sr) * HIDDEN + k0 + sc);
        bf16x8 a1 = *(const bf16x8*)(xb + (size_t)(m0 + sr + 64) * HIDDEN + k0 + sc);
        bf16x8 b0 = *(const bf16x8*)(Wz + (size_t)sr * HIDDEN + k0 + sc);
        bf16x8 b1 = *(const bf16x8*)(Wz + (size_t)(sr + 64) * HIDDEN + k0 + sc);
        __syncthreads();
        *(bf16x8*)(Ash + sr * 40 + sc) = a0;
        *(bf16x8*)(Ash + (sr + 64) * 40 + sc) = a1;
        *(bf16x8*)(Bsh + sr * 40 + sc) = b0;
        *(bf16x8*)(Bsh + (sr + 64) * 40 + sc) = b1;
        __syncthreads();
        bf16x8 af[4], bfr[4];
        for (int mi = 0; mi < 4; mi++)
            af[mi] = *(const bf16x8*)(Ash + (wm + mi * 16 + l16) * 40 + quad * 8);
        for (int ni = 0; ni < 4; ni++)
            bfr[ni] = *(const bf16x8*)(Bsh + (wn + ni * 16 + l16) * 40 + quad * 8);
        for (int mi = 0; mi < 4; mi++)
            for (int ni = 0; ni < 4; ni++)
                acc[mi][ni] = __builtin_amdgcn_mfma_f32_16x16x32_bf16(af[mi], bfr[ni], acc[mi][ni], 0, 0, 0);
    }

    const size_t base = (size_t)head * (MTOT * HDIM);
    if (type == 0) {
        for (int mi = 0; mi < 4; mi++)
            for (int ni = 0; ni < 4; ni++)
                for (int r = 0; r < 4; r++) {
                    int m = m0 + wm + mi * 16 + quad * 4 + r;
                    int n = wn + ni * 16 + l16;
                    Q[base + (size_t)m * HDIM + n] = f2bf(acc[mi][ni][r] * 0.08838834764831845f);
                }
    } else if (type == 1) {
        for (int mi = 0; mi < 4; mi++)
            for (int ni = 0; ni < 4; ni++)
                for (int r = 0; r < 4; r++) {
                    int m = m0 + wm + mi * 16 + quad * 4 + r;
                    int n = wn + ni * 16 + l16;
                    Kk[base + (size_t)m * HDIM + n] = f2bf(acc[mi][ni][r]);
                }
    } else {
        for (int mi = 0; mi < 4; mi++)
            for (int ni = 0; ni < 4; ni++) {
                int m = m0 + wm + mi * 16 + quad * 4;   // 4 consecutive tokens
                int bb = m >> 11, t = m & 2047;
                int n = wn + ni * 16 + l16;
                short4 o;
                o.x = f2bf(acc[mi][ni][0]); o.y = f2bf(acc[mi][ni][1]);
                o.z = f2bf(acc[mi][ni][2]); o.w = f2bf(acc[mi][ni][3]);
                *(short4*)(Vt + base + (size_t)bb * (HDIM * TT) + (size_t)n * TT + t) = o;
            }
    }
}

// ---------------- kernel 3: fano flash attention (no K/V LDS) ----------------
// grid: (T/64=32, B=4, HEADS=7), block 256 (4 waves, each owns 16 q-rows)
__global__ __launch_bounds__(256) void fano_attn(
    const short* __restrict__ Q, const short* __restrict__ K, const short* __restrict__ Vt,
    short* __restrict__ Ocat, const int* __restrict__ iscp)
{
    __shared__ short Ps[4][16 * 72];

    const int causal = *iscp;
    const int qt = causal ? ((int)gridDim.x - 1 - blockIdx.x) : blockIdx.x;
    const int q0 = qt * 64;
    const int b = blockIdx.y, h = blockIdx.z;
    const int tid = threadIdx.x, wave = tid >> 6, lane = tid & 63;
    const int quad = lane >> 4, l16 = lane & 15;

    const short* Qb = Q + (size_t)(h * MTOT + b * TT + q0) * HDIM;
    const short* Kb = K + (size_t)(h * MTOT + b * TT) * HDIM;
    const short* Vb = Vt + (size_t)h * MTOT * HDIM + (size_t)b * HDIM * TT;

    bf16x8 qf[4];
    for (int ks = 0; ks < 4; ks++)
        qf[ks] = *(const bf16x8*)(Qb + (size_t)(wave * 16 + l16) * HDIM + ks * 32 + quad * 8);

    float mrun[4], lrun[4];
    f32x4 oacc[8] = {};
    int irow[4];
    for (int r = 0; r < 4; r++) {
        mrun[r] = -1e30f; lrun[r] = 0.f;
        irow[r] = q0 + wave * 16 + quad * 4 + r;
    }

    int d7b = (l16 - h + 7) % 7;   // (s - h) mod 7 for s = s0 + l16, s0 = 0
    short* Pw = &Ps[wave][0];

    const int send = causal ? (q0 + 64) : TT;
    for (int s0 = 0; s0 < send; s0 += 64) {
        // S = Q K^T  (K frags direct from global)
        f32x4 sacc[4] = {};
        const short* Kt = Kb + (size_t)s0 * HDIM;
        for (int ni = 0; ni < 4; ni++) {
            const short* kp = Kt + (size_t)(ni * 16 + l16) * HDIM + quad * 8;
            bf16x8 k0v = *(const bf16x8*)(kp);
            bf16x8 k1v = *(const bf16x8*)(kp + 32);
            bf16x8 k2v = *(const bf16x8*)(kp + 64);
            bf16x8 k3v = *(const bf16x8*)(kp + 96);
            sacc[ni] = __builtin_amdgcn_mfma_f32_16x16x32_bf16(qf[0], k0v, sacc[ni], 0, 0, 0);
            sacc[ni] = __builtin_amdgcn_mfma_f32_16x16x32_bf16(qf[1], k1v, sacc[ni], 0, 0, 0);
            sacc[ni] = __builtin_amdgcn_mfma_f32_16x16x32_bf16(qf[2], k2v, sacc[ni], 0, 0, 0);
            sacc[ni] = __builtin_amdgcn_mfma_f32_16x16x32_bf16(qf[3], k3v, sacc[ni], 0, 0, 0);
        }

        // fano mask + row max (scale already folded into Q)
        float mx[4] = {-1e30f, -1e30f, -1e30f, -1e30f};
        for (int ni = 0; ni < 4; ni++) {
            int d7 = d7b + 2 * ni; if (d7 >= 7) d7 -= 7;   // 16 mod 7 == 2
            bool line = (0x0B >> d7) & 1;                   // d7 in {0,1,3}
            int s = s0 + ni * 16 + l16;
            for (int r = 0; r < 4; r++) {
                int i = irow[r];
                bool ok = causal ? ((s <= i) & (line | (s >= i - 16)))
                                 : (line | ((s >= i - 16) & (s <= i + 16)));
                float v = ok ? sacc[ni][r] : -1e30f;
                sacc[ni][r] = v;
                mx[r] = fmaxf(mx[r], v);
            }
        }
        d7b++; if (d7b == 7) d7b = 0;                        // 64 mod 7 == 1

        for (int off = 1; off < 16; off <<= 1)
            for (int r = 0; r < 4; r++) mx[r] = fmaxf(mx[r], __shfl_xor(mx[r], off));

        float alpha[4], rs[4];
        for (int r = 0; r < 4; r++) {
            float nm = fmaxf(mrun[r], mx[r]);
            alpha[r] = __expf(mrun[r] - nm);
            mrun[r] = nm;
            rs[r] = 0.f;
        }
        for (int ni = 0; ni < 4; ni++)
            for (int r = 0; r < 4; r++) {
                float p = __expf(sacc[ni][r] - mrun[r]);
                sacc[ni][r] = p;
                rs[r] += p;
            }
        for (int off = 1; off < 16; off <<= 1)
            for (int r = 0; r < 4; r++) rs[r] += __shfl_xor(rs[r], off);
        for (int r = 0; r < 4; r++) lrun[r] = lrun[r] * alpha[r] + rs[r];
        for (int nj = 0; nj < 8; nj++)
            for (int r = 0; r < 4; r++) oacc[nj][r] *= alpha[r];

        // P: C-layout regs -> wave-private LDS -> A-layout frags (no barrier needed)
        for (int ni = 0; ni < 4; ni++)
            for (int r = 0; r < 4; r++)
                Pw[(quad * 4 + r) * 72 + ni * 16 + l16] = f2bf(sacc[ni][r]);

        // O += P V  (V^T frags direct from global)
        const short* Vt0 = Vb + s0;
        for (int ks2 = 0; ks2 < 2; ks2++) {
            bf16x8 ap = *(const bf16x8*)(Pw + l16 * 72 + ks2 * 32 + quad * 8);
            for (int nj = 0; nj < 8; nj++) {
                bf16x8 bv = *(const bf16x8*)(Vt0 + (size_t)(nj * 16 + l16) * TT + ks2 * 32 + quad * 8);
                oacc[nj] = __builtin_amdgcn_mfma_f32_16x16x32_bf16(ap, bv, oacc[nj], 0, 0, 0);
            }
        }
    }

    // epilogue
    float inv[4];
    for (int r = 0; r < 4; r++) inv[r] = 1.0f / lrun[r];
    short* Obase = Ocat + (size_t)(b * TT) * HIDDEN + h * HDIM;
    for (int nj = 0; nj < 8; nj++)
        for (int r = 0; r < 4; r++)
            Obase[(size_t)irow[r] * HIDDEN + nj * 16 + l16] = f2bf(oacc[nj][r] * inv[r]);
}

// ---------------- kernel 4: output projection (128x128 tile) ----------------
// out[m][n] = sum_k Ocat[m][k] * Wo_b[n][k]; grid (64, 7), block 256
__global__ __launch_bounds__(256) void out_gemm(
    const short* __restrict__ A, const short* __restrict__ Bt, float* __restrict__ out)
{
    __shared__ short Ash[128 * 40];
    __shared__ short Bsh[128 * 40];
    const int m0 = blockIdx.x * 128;
    const int n0 = blockIdx.y * 128;

    const int tid = threadIdx.x;
    const int wave = tid >> 6, lane = tid & 63;
    const int quad = lane >> 4, l16 = lane & 15;
    const int wm = (wave >> 1) * 64, wn = (wave & 1) * 64;

    f32x4 acc[4][4] = {};
    const int sr = tid >> 2, sc = (tid & 3) * 8;

    for (int k0 = 0; k0 < HIDDEN; k0 += 32) {
        bf16x8 a0 = *(const bf16x8*)(A + (size_t)(m0 + sr) * HIDDEN + k0 + sc);
        bf16x8 a1 = *(const bf16x8*)(A + (size_t)(m0 + sr + 64) * HIDDEN + k0 + sc);
        bf16x8 b0 = *(const bf16x8*)(Bt + (size_t)(n0 + sr) * HIDDEN + k0 + sc);
        bf16x8 b1 = *(const bf16x8*)(Bt + (size_t)(n0 + sr + 64) * HIDDEN + k0 + sc);
        __syncthreads();
        *(bf16x8*)(Ash + sr * 40 + sc) = a0;
        *(bf16x8*)(Ash + (sr + 64) * 40 + sc) = a1;
        *(bf16x8*)(Bsh + sr * 40 + sc) = b0;
        *(bf16x8*)(Bsh + (sr + 64) * 40 + sc) = b1;
        __syncthreads();
        bf16x8 af[4], bfr[4];
        for (int mi = 0; mi < 4; mi++)
            af[mi] = *(const bf16x8*)(Ash + (wm + mi * 16 + l16) * 40 + quad * 8);
        for (int ni = 0; ni < 4; ni++)
            bfr[ni] = *(const bf16x8*)(Bsh + (wn + ni * 16 + l16) * 40 + quad * 8);
        for (int mi = 0; mi < 4; mi++)
            for (int ni = 0; ni < 4; ni++)
                acc[mi][ni] = __builtin_amdgcn_mfma_f32_16x16x32_bf16(af[mi], bfr[ni], acc[mi][ni], 0, 0, 0);
    }

    for (int mi = 0; mi < 4; mi++)
        for (int ni = 0; ni < 4; ni++)
            for (int r = 0; r < 4; r++) {
                int m = m0 + wm + mi * 16 + quad * 4 + r;
                int n = n0 + wn + ni * 16 + l16;
                out[(size_t)m * HIDDEN + n] = acc[mi][ni][r];
            }
}

extern "C" void kernel_launch(void* const* d_in, const int* in_sizes, int n_in,
                              void* d_out, int out_size, void* d_ws, size_t ws_size,
                              hipStream_t stream) {
    (void)in_sizes; (void)n_in; (void)out_size; (void)ws_size;
    const float* x  = (const float*)d_in[0];
    const float* Wq = (const float*)d_in[1];
    const float* Wk = (const float*)d_in[2];
    const float* Wv = (const float*)d_in[3];
    const float* Wo = (const float*)d_in[4];
    const int* iscp = (const int*)d_in[5];
    float* out = (float*)d_out;

    short* xb   = (short*)d_ws;                       // 8192*896
    short* Qb   = xb   + (size_t)MTOT * HIDDEN;       // 7*8192*128
    short* Kb   = Qb   + (size_t)HEADS * MTOT * HDIM;
    short* Vtb  = Kb   + (size_t)HEADS * MTOT * HDIM;
    short* Ocat = Vtb  + (size_t)HEADS * MTOT * HDIM; // 8192*896  (aliased with Wt)
    short* Wt   = Ocat;                               // 21*128*896 bf16, used only before attn
    short* Wob  = Ocat + (size_t)MTOT * HIDDEN;       // 896*896

    cast_x_kernel<<<(MTOT * HIDDEN) / (256 * 4), 256, 0, stream>>>(x, xb);
    cast_wo_kernel<<<(HIDDEN * HIDDEN) / (256 * 4), 256, 0, stream>>>(Wo, Wob);
    transpose_cast_w<<<dim3(HIDDEN / 32, HDIM / 32, 21), 256, 0, stream>>>(Wq, Wk, Wv, Wt);
    qkv_gemm<<<dim3(MTOT / 128, 21), 256, 0, stream>>>(xb, Wt, Qb, Kb, Vtb);
    fano_attn<<<dim3(TT / 64, BB, HEADS), 256, 0, stream>>>(Qb, Kb, Vtb, Ocat, iscp);
    out_gemm<<<dim3(MTOT / 128, HIDDEN / 128), 256, 0, stream>>>(Ocat, Wob, out);
}

// Round 3
// 400.569 us; speedup vs baseline: 1.8322x; 1.8322x over previous
//
#include <hip/hip_runtime.h>
#include <hip/hip_bf16.h>

#define HIDDEN 896
#define HEADS 7
#define HDIM 128
#define BB 4
#define TT 2048
#define MTOT (BB*TT)   // 8192

typedef short bf16x8 __attribute__((ext_vector_type(8)));
typedef float f32x4 __attribute__((ext_vector_type(4)));

__device__ __forceinline__ short f2bf(float f) {
    union { float f; unsigned u; } v; v.f = f;
    unsigned r = (v.u + 0x7FFF + ((v.u >> 16) & 1)) >> 16;
    return (short)r;
}

// ---------------- kernel 1: cast x (fp32) -> bf16 ----------------
__global__ __launch_bounds__(256) void cast_x_kernel(const float* __restrict__ x,
                                                     short* __restrict__ xb) {
    int base = (blockIdx.x * 256 + threadIdx.x) * 4;
    if (base < MTOT * HIDDEN) {
        float4 v = *(const float4*)(x + base);
        short4 o;
        o.x = f2bf(v.x); o.y = f2bf(v.y); o.z = f2bf(v.z); o.w = f2bf(v.w);
        *(short4*)(xb + base) = o;
    }
}

// cast Wo fp32[896][896] -> bf16 (already B^T form [n][k])
__global__ __launch_bounds__(256) void cast_wo_kernel(const float* __restrict__ src,
                                                      short* __restrict__ dst) {
    int base = (blockIdx.x * 256 + threadIdx.x) * 4;
    if (base < HIDDEN * HIDDEN) {
        float4 v = *(const float4*)(src + base);
        short4 o;
        o.x = f2bf(v.x); o.y = f2bf(v.y); o.z = f2bf(v.z); o.w = f2bf(v.w);
        *(short4*)(dst + base) = o;
    }
}

// transpose-cast Wq/Wk/Wv fp32 [head][896 k][128 n] -> bf16 Wt[type*7+head][128 n][896 k]
__global__ __launch_bounds__(256) void transpose_cast_w(
    const float* __restrict__ Wq, const float* __restrict__ Wk,
    const float* __restrict__ Wv, short* __restrict__ Wt)
{
    __shared__ float tile[32][33];
    const int z = blockIdx.z;
    const int type = z / 7, head = z % 7;
    const float* src = (type == 0 ? Wq : (type == 1 ? Wk : Wv)) + head * (HIDDEN * HDIM);
    short* dst = Wt + (size_t)z * (HDIM * HIDDEN);
    const int r0 = blockIdx.x * 32, c0 = blockIdx.y * 32;
    const int tx = threadIdx.x & 31, ty = threadIdx.x >> 5;  // 32 x 8
    for (int i = 0; i < 4; i++)
        tile[ty * 4 + i][tx] = src[(r0 + ty * 4 + i) * HDIM + c0 + tx];
    __syncthreads();
    for (int i = 0; i < 4; i++)
        dst[(c0 + ty * 4 + i) * HIDDEN + r0 + tx] = f2bf(tile[tx][ty * 4 + i]);
}

// ---------------- kernel 2: QKV projection GEMM (128x128 tile) ----------------
__global__ __launch_bounds__(256) void qkv_gemm(
    const short* __restrict__ xb, const short* __restrict__ Wt,
    short* __restrict__ Q, short* __restrict__ Kk, short* __restrict__ Vt)
{
    __shared__ short Ash[128 * 40];
    __shared__ short Bsh[128 * 40];
    const int m0 = blockIdx.x * 128;
    const int z = blockIdx.y;
    const int head = z % 7, type = z / 7;
    const short* Wz = Wt + (size_t)z * (HDIM * HIDDEN);

    const int tid = threadIdx.x;
    const int wave = tid >> 6, lane = tid & 63;
    const int quad = lane >> 4, l16 = lane & 15;
    const int wm = (wave >> 1) * 64, wn = (wave & 1) * 64;

    f32x4 acc[4][4] = {};
    const int sr = tid >> 2, sc = (tid & 3) * 8;

    for (int k0 = 0; k0 < HIDDEN; k0 += 32) {
        bf16x8 a0 = *(const bf16x8*)(xb + (size_t)(m0 + sr) * HIDDEN + k0 + sc);
        bf16x8 a1 = *(const bf16x8*)(xb + (size_t)(m0 + sr + 64) * HIDDEN + k0 + sc);
        bf16x8 b0 = *(const bf16x8*)(Wz + (size_t)sr * HIDDEN + k0 + sc);
        bf16x8 b1 = *(const bf16x8*)(Wz + (size_t)(sr + 64) * HIDDEN + k0 + sc);
        __syncthreads();
        *(bf16x8*)(Ash + sr * 40 + sc) = a0;
        *(bf16x8*)(Ash + (sr + 64) * 40 + sc) = a1;
        *(bf16x8*)(Bsh + sr * 40 + sc) = b0;
        *(bf16x8*)(Bsh + (sr + 64) * 40 + sc) = b1;
        __syncthreads();
        bf16x8 af[4], bfr[4];
        for (int mi = 0; mi < 4; mi++)
            af[mi] = *(const bf16x8*)(Ash + (wm + mi * 16 + l16) * 40 + quad * 8);
        for (int ni = 0; ni < 4; ni++)
            bfr[ni] = *(const bf16x8*)(Bsh + (wn + ni * 16 + l16) * 40 + quad * 8);
        for (int mi = 0; mi < 4; mi++)
            for (int ni = 0; ni < 4; ni++)
                acc[mi][ni] = __builtin_amdgcn_mfma_f32_16x16x32_bf16(af[mi], bfr[ni], acc[mi][ni], 0, 0, 0);
    }

    const size_t base = (size_t)head * (MTOT * HDIM);
    if (type == 0) {
        for (int mi = 0; mi < 4; mi++)
            for (int ni = 0; ni < 4; ni++)
                for (int r = 0; r < 4; r++) {
                    int m = m0 + wm + mi * 16 + quad * 4 + r;
                    int n = wn + ni * 16 + l16;
                    Q[base + (size_t)m * HDIM + n] = f2bf(acc[mi][ni][r] * 0.08838834764831845f);
                }
    } else if (type == 1) {
        for (int mi = 0; mi < 4; mi++)
            for (int ni = 0; ni < 4; ni++)
                for (int r = 0; r < 4; r++) {
                    int m = m0 + wm + mi * 16 + quad * 4 + r;
                    int n = wn + ni * 16 + l16;
                    Kk[base + (size_t)m * HDIM + n] = f2bf(acc[mi][ni][r]);
                }
    } else {
        for (int mi = 0; mi < 4; mi++)
            for (int ni = 0; ni < 4; ni++) {
                int m = m0 + wm + mi * 16 + quad * 4;
                int bb = m >> 11, t = m & 2047;
                int n = wn + ni * 16 + l16;
                short4 o;
                o.x = f2bf(acc[mi][ni][0]); o.y = f2bf(acc[mi][ni][1]);
                o.z = f2bf(acc[mi][ni][2]); o.w = f2bf(acc[mi][ni][3]);
                *(short4*)(Vt + base + (size_t)bb * (HDIM * TT) + (size_t)n * TT + t) = o;
            }
    }
}

// ---------------- kernel 3: fano flash attention v3 ----------------
// 128-row q-tile per block, LDS-staged K/V with register-prefetch pipeline.
// grid: (T/128=16, B=4, HEADS=7), block 256 (4 waves, each owns 32 q-rows)
__global__ __launch_bounds__(256, 2) void fano_attn(
    const short* __restrict__ Q, const short* __restrict__ K, const short* __restrict__ Vt,
    short* __restrict__ Ocat, const int* __restrict__ iscp)
{
    __shared__ short Ks[64 * 136];
    __shared__ short Vs[128 * 72];
    __shared__ short Ps[4][32 * 72];

    const int causal = *iscp;
    const int qt = causal ? ((int)gridDim.x - 1 - blockIdx.x) : blockIdx.x;
    const int q0 = qt * 128;
    const int b = blockIdx.y, h = blockIdx.z;
    const int tid = threadIdx.x, wave = tid >> 6, lane = tid & 63;
    const int quad = lane >> 4, l16 = lane & 15;

    const short* Qb = Q + (size_t)(h * MTOT + b * TT + q0) * HDIM;
    const short* Kb = K + (size_t)(h * MTOT + b * TT) * HDIM;
    const short* Vb = Vt + (size_t)h * MTOT * HDIM + (size_t)b * HDIM * TT;

    // Q fragments direct from global (one-time; scale folded in at projection)
    bf16x8 qf[2][4];
    for (int g = 0; g < 2; g++)
        for (int ks = 0; ks < 4; ks++)
            qf[g][ks] = *(const bf16x8*)(Qb + (size_t)(wave * 32 + g * 16 + l16) * HDIM + ks * 32 + quad * 8);

    float mrun[2][4], lrun[2][4];
    f32x4 oacc[2][8] = {};
    int irow[2][4];
    for (int g = 0; g < 2; g++)
        for (int r = 0; r < 4; r++) {
            mrun[g][r] = -1e30f; lrun[g][r] = 0.f;
            irow[g][r] = q0 + wave * 32 + g * 16 + quad * 4 + r;
        }

    // staging index maps (16B chunks, 4 per thread per tile)
    int krow[4], kcol[4], vrow[4], vcol[4];
    for (int i = 0; i < 4; i++) {
        int c = tid + i * 256;
        krow[i] = c >> 4; kcol[i] = (c & 15) * 8;   // K: 64 rows x 128
        vrow[i] = c >> 3; vcol[i] = (c & 7) * 8;    // V^T: 128 rows x 64
    }

    const int send = causal ? (q0 + 128) : TT;

    // prologue prefetch (tile s0 = 0)
    bf16x8 kreg[4], vreg[4];
    for (int i = 0; i < 4; i++) {
        kreg[i] = *(const bf16x8*)(Kb + (size_t)krow[i] * HDIM + kcol[i]);
        vreg[i] = *(const bf16x8*)(Vb + (size_t)vrow[i] * TT + vcol[i]);
    }

    int d7b = (l16 - h + 7) % 7;   // (s - h) mod 7 at s = s0 + l16, s0 = 0
    short* Pw = &Ps[wave][0];

    for (int s0 = 0; s0 < send; s0 += 64) {
        __syncthreads();
        for (int i = 0; i < 4; i++) {
            *(bf16x8*)(Ks + krow[i] * 136 + kcol[i]) = kreg[i];
            *(bf16x8*)(Vs + vrow[i] * 72 + vcol[i]) = vreg[i];
        }
        __syncthreads();

        // prefetch next tile (clamped: redundant reload of current on last iter)
        int sn = s0 + 64; if (sn >= send) sn = s0;
        const short* Kn = Kb + (size_t)sn * HDIM;
        const short* Vn = Vb + sn;
        for (int i = 0; i < 4; i++) {
            kreg[i] = *(const bf16x8*)(Kn + (size_t)krow[i] * HDIM + kcol[i]);
            vreg[i] = *(const bf16x8*)(Vn + (size_t)vrow[i] * TT + vcol[i]);
        }

        // S = Q K^T
        f32x4 sacc[2][4] = {};
        for (int ni = 0; ni < 4; ni++)
            for (int ks = 0; ks < 4; ks++) {
                bf16x8 bk = *(const bf16x8*)(Ks + (ni * 16 + l16) * 136 + ks * 32 + quad * 8);
                sacc[0][ni] = __builtin_amdgcn_mfma_f32_16x16x32_bf16(qf[0][ks], bk, sacc[0][ni], 0, 0, 0);
                sacc[1][ni] = __builtin_amdgcn_mfma_f32_16x16x32_bf16(qf[1][ks], bk, sacc[1][ni], 0, 0, 0);
            }

        // fano mask + row max
        float mx[2][4];
        for (int g = 0; g < 2; g++)
            for (int r = 0; r < 4; r++) mx[g][r] = -1e30f;
        for (int ni = 0; ni < 4; ni++) {
            int d7 = d7b + 2 * ni; if (d7 >= 7) d7 -= 7;
            bool line = (0x0B >> d7) & 1;
            int s = s0 + ni * 16 + l16;
            for (int g = 0; g < 2; g++)
                for (int r = 0; r < 4; r++) {
                    int i = irow[g][r];
                    bool ok = causal ? ((s <= i) & (line | (s >= i - 16)))
                                     : (line | ((s >= i - 16) & (s <= i + 16)));
                    float v = ok ? sacc[g][ni][r] : -1e30f;
                    sacc[g][ni][r] = v;
                    mx[g][r] = fmaxf(mx[g][r], v);
                }
        }
        d7b++; if (d7b == 7) d7b = 0;

        for (int off = 1; off < 16; off <<= 1)
            for (int g = 0; g < 2; g++)
                for (int r = 0; r < 4; r++)
                    mx[g][r] = fmaxf(mx[g][r], __shfl_xor(mx[g][r], off));

        float alpha[2][4], rs[2][4];
        for (int g = 0; g < 2; g++)
            for (int r = 0; r < 4; r++) {
                float nm = fmaxf(mrun[g][r], mx[g][r]);
                alpha[g][r] = __expf(mrun[g][r] - nm);
                mrun[g][r] = nm;
                rs[g][r] = 0.f;
            }
        for (int ni = 0; ni < 4; ni++)
            for (int g = 0; g < 2; g++)
                for (int r = 0; r < 4; r++) {
                    float p = __expf(sacc[g][ni][r] - mrun[g][r]);
                    sacc[g][ni][r] = p;
                    rs[g][r] += p;
                }
        for (int off = 1; off < 16; off <<= 1)
            for (int g = 0; g < 2; g++)
                for (int r = 0; r < 4; r++)
                    rs[g][r] += __shfl_xor(rs[g][r], off);
        for (int g = 0; g < 2; g++)
            for (int r = 0; r < 4; r++)
                lrun[g][r] = lrun[g][r] * alpha[g][r] + rs[g][r];
        for (int g = 0; g < 2; g++)
            for (int nj = 0; nj < 8; nj++)
                for (int r = 0; r < 4; r++) oacc[g][nj][r] *= alpha[g][r];

        // P: C-layout regs -> wave-private LDS -> A-layout frags
        for (int g = 0; g < 2; g++)
            for (int ni = 0; ni < 4; ni++)
                for (int r = 0; r < 4; r++)
                    Pw[(g * 16 + quad * 4 + r) * 72 + ni * 16 + l16] = f2bf(sacc[g][ni][r]);

        // O += P V
        for (int ks2 = 0; ks2 < 2; ks2++) {
            bf16x8 ap0 = *(const bf16x8*)(Pw + l16 * 72 + ks2 * 32 + quad * 8);
            bf16x8 ap1 = *(const bf16x8*)(Pw + (16 + l16) * 72 + ks2 * 32 + quad * 8);
            for (int nj = 0; nj < 8; nj++) {
                bf16x8 bv = *(const bf16x8*)(Vs + (nj * 16 + l16) * 72 + ks2 * 32 + quad * 8);
                oacc[0][nj] = __builtin_amdgcn_mfma_f32_16x16x32_bf16(ap0, bv, oacc[0][nj], 0, 0, 0);
                oacc[1][nj] = __builtin_amdgcn_mfma_f32_16x16x32_bf16(ap1, bv, oacc[1][nj], 0, 0, 0);
            }
        }
    }

    // epilogue
    short* Obase = Ocat + (size_t)(b * TT) * HIDDEN + h * HDIM;
    for (int g = 0; g < 2; g++) {
        float inv[4];
        for (int r = 0; r < 4; r++) inv[r] = 1.0f / lrun[g][r];
        for (int nj = 0; nj < 8; nj++)
            for (int r = 0; r < 4; r++)
                Obase[(size_t)irow[g][r] * HIDDEN + nj * 16 + l16] = f2bf(oacc[g][nj][r] * inv[r]);
    }
}

// ---------------- kernel 4: output projection (128x128 tile) ----------------
__global__ __launch_bounds__(256) void out_gemm(
    const short* __restrict__ A, const short* __restrict__ Bt, float* __restrict__ out)
{
    __shared__ short Ash[128 * 40];
    __shared__ short Bsh[128 * 40];
    const int m0 = blockIdx.x * 128;
    const int n0 = blockIdx.y * 128;

    const int tid = threadIdx.x;
    const int wave = tid >> 6, lane = tid & 63;
    const int quad = lane >> 4, l16 = lane & 15;
    const int wm = (wave >> 1) * 64, wn = (wave & 1) * 64;

    f32x4 acc[4][4] = {};
    const int sr = tid >> 2, sc = (tid & 3) * 8;

    for (int k0 = 0; k0 < HIDDEN; k0 += 32) {
        bf16x8 a0 = *(const bf16x8*)(A + (size_t)(m0 + sr) * HIDDEN + k0 + sc);
        bf16x8 a1 = *(const bf16x8*)(A + (size_t)(m0 + sr + 64) * HIDDEN + k0 + sc);
        bf16x8 b0 = *(const bf16x8*)(Bt + (size_t)(n0 + sr) * HIDDEN + k0 + sc);
        bf16x8 b1 = *(const bf16x8*)(Bt + (size_t)(n0 + sr + 64) * HIDDEN + k0 + sc);
        __syncthreads();
        *(bf16x8*)(Ash + sr * 40 + sc) = a0;
        *(bf16x8*)(Ash + (sr + 64) * 40 + sc) = a1;
        *(bf16x8*)(Bsh + sr * 40 + sc) = b0;
        *(bf16x8*)(Bsh + (sr + 64) * 40 + sc) = b1;
        __syncthreads();
        bf16x8 af[4], bfr[4];
        for (int mi = 0; mi < 4; mi++)
            af[mi] = *(const bf16x8*)(Ash + (wm + mi * 16 + l16) * 40 + quad * 8);
        for (int ni = 0; ni < 4; ni++)
            bfr[ni] = *(const bf16x8*)(Bsh + (wn + ni * 16 + l16) * 40 + quad * 8);
        for (int mi = 0; mi < 4; mi++)
            for (int ni = 0; ni < 4; ni++)
                acc[mi][ni] = __builtin_amdgcn_mfma_f32_16x16x32_bf16(af[mi], bfr[ni], acc[mi][ni], 0, 0, 0);
    }

    for (int mi = 0; mi < 4; mi++)
        for (int ni = 0; ni < 4; ni++)
            for (int r = 0; r < 4; r++) {
                int m = m0 + wm + mi * 16 + quad * 4 + r;
                int n = n0 + wn + ni * 16 + l16;
                out[(size_t)m * HIDDEN + n] = acc[mi][ni][r];
            }
}

extern "C" void kernel_launch(void* const* d_in, const int* in_sizes, int n_in,
                              void* d_out, int out_size, void* d_ws, size_t ws_size,
                              hipStream_t stream) {
    (void)in_sizes; (void)n_in; (void)out_size; (void)ws_size;
    const float* x  = (const float*)d_in[0];
    const float* Wq = (const float*)d_in[1];
    const float* Wk = (const float*)d_in[2];
    const float* Wv = (const float*)d_in[3];
    const float* Wo = (const float*)d_in[4];
    const int* iscp = (const int*)d_in[5];
    float* out = (float*)d_out;

    short* xb   = (short*)d_ws;                       // 8192*896
    short* Qb   = xb   + (size_t)MTOT * HIDDEN;       // 7*8192*128
    short* Kb   = Qb   + (size_t)HEADS * MTOT * HDIM;
    short* Vtb  = Kb   + (size_t)HEADS * MTOT * HDIM;
    short* Ocat = Vtb  + (size_t)HEADS * MTOT * HDIM; // 8192*896  (aliased with Wt)
    short* Wt   = Ocat;                               // 21*128*896 bf16, used only before attn
    short* Wob  = Ocat + (size_t)MTOT * HIDDEN;       // 896*896

    cast_x_kernel<<<(MTOT * HIDDEN) / (256 * 4), 256, 0, stream>>>(x, xb);
    cast_wo_kernel<<<(HIDDEN * HIDDEN) / (256 * 4), 256, 0, stream>>>(Wo, Wob);
    transpose_cast_w<<<dim3(HIDDEN / 32, HDIM / 32, 21), 256, 0, stream>>>(Wq, Wk, Wv, Wt);
    qkv_gemm<<<dim3(MTOT / 128, 21), 256, 0, stream>>>(xb, Wt, Qb, Kb, Vtb);
    fano_attn<<<dim3(TT / 128, BB, HEADS), 256, 0, stream>>>(Qb, Kb, Vtb, Ocat, iscp);
    out_gemm<<<dim3(MTOT / 128, HIDDEN / 128), 256, 0, stream>>>(Ocat, Wob, out);
}